// Round 8
// baseline (124.862 us; speedup 1.0000x reference)
//
#include <hip/hip_runtime.h>
#include <hip/hip_fp16.h>

#define N_DET 128
#define N_T   2048
#define NPIX  65536   // 256*256
#define G 4           // det rows per K-iter (4 x 16 KB = 64 KB per LDS buffer)
#define NITER (N_DET / G)  // 32
#define PT 256        // pixels per block
#define TPB 1024      // threads: 256 px x 4 det-slots

typedef float f4_t __attribute__((ext_vector_type(4)));

// Kernel 1: transpose+pack sino (B, N_DET, N_T) fp32 -> ws (N_DET, N_T) of
// 8-byte records { s_t[b0..b3] } as 4 fp16 (ws = 2 MB, L2-resident).
__global__ __launch_bounds__(256) void sino_pack_kernel(
    const float* __restrict__ sino, float2* __restrict__ ws) {
  const int idx = blockIdx.x * blockDim.x + threadIdx.x;  // idx = d*N_T + t
  const __half2 lo = __floats2half2_rn(
      __builtin_nontemporal_load(sino + 0 * N_DET * N_T + idx),
      __builtin_nontemporal_load(sino + 1 * N_DET * N_T + idx));
  const __half2 hi = __floats2half2_rn(
      __builtin_nontemporal_load(sino + 2 * N_DET * N_T + idx),
      __builtin_nontemporal_load(sino + 3 * N_DET * N_T + idx));
  union { struct { __half2 a, b; } h; float2 f; } u;
  u.h.a = lo;
  u.h.b = hi;
  ws[idx] = u.f;
}

// Kernel 2: K-loop kernel. Block = 256-pixel tile x ALL 128 dets (single
// writer per output -> no atomics, no zero-init). 1024 threads = 256 px x
// 4 det-slots. Loop over 32 det groups of G=4 rows, double-buffered LDS
// (2 x 64 KB): stage group g+1 into registers, compute group g, commit
// registers to the other LDS buffer, one barrier per iter.
__global__ __launch_bounds__(TPB, 4) void das_kloop_kernel(
    const float* __restrict__ lut, const float2* __restrict__ ws,
    float* __restrict__ out) {
  __shared__ float2 sbuf[2][G * N_T];  // 2 x 64 KB
  __shared__ float apod_s[N_DET];      // 512 B

  const int tid = threadIdx.x;   // 0..1023
  const int px_l = tid >> 2;     // 0..255 pixel within tile
  const int slot = tid & 3;      // det slot within current group
  const int p = blockIdx.x * PT + px_l;

  if (tid < N_DET) {
    apod_s[tid] = 0.5f - 0.5f * cosf(6.28318530717958647692f *
                                     ((float)tid / (float)(N_DET - 1)));
  }

  // Stage group 0 into buffer 0 (4 float4 per thread, coalesced from ws).
  {
    const float4* src = reinterpret_cast<const float4*>(ws);
    float4* dst = reinterpret_cast<float4*>(&sbuf[0][0]);
#pragma unroll
    for (int i = 0; i < 4; ++i) dst[tid + i * TPB] = src[tid + i * TPB];
  }

  // lut pointer for this (pixel, slot): det d = g*4 + slot each iteration.
  // Lanes 4k..4k+3 of a wave read one pixel's contiguous 32 B chunk ->
  // 16 lines per wave-inst; consecutive iters hit the other half in L1.
  const float2* lutp =
      reinterpret_cast<const float2*>(lut) + (size_t)p * N_DET + slot;
  float2 lcur = lutp[0];

  __syncthreads();

  float a0 = 0.f, a1 = 0.f, a2 = 0.f, a3 = 0.f;

  for (int g = 0; g < NITER; ++g) {
    const bool more = (g + 1 < NITER);

    // Issue next group's staging loads + lut load FIRST (independent of LDS).
    float4 st[4];
    float2 lnext;
    if (more) {
      const float4* src =
          reinterpret_cast<const float4*>(ws + (size_t)(g + 1) * G * N_T);
#pragma unroll
      for (int i = 0; i < 4; ++i) st[i] = src[tid + i * TPB];
      lnext = lutp[(size_t)(g + 1) * G];
    }

    // Compute group g from the current LDS buffer.
    const float2* sb = sbuf[g & 1];
    const float tof = lcur.x;
    const float al = lcur.y;
    const float kf = floorf(tof);
    const bool valid = (kf >= 0.0f) && (kf < (float)(N_T - 1));
    const int k0 = (int)fminf(fmaxf(kf, 0.0f), (float)(N_T - 2));
    const float w = valid ? apod_s[g * G + slot] : 0.0f;  // 4 addrs -> broadcast

    const float2 r0 = sb[slot * N_T + k0];      // ds_read2_b64: taps t, t+1
    const float2 r1 = sb[slot * N_T + k0 + 1];
    const __half2* h0 = reinterpret_cast<const __half2*>(&r0);
    const __half2* h1 = reinterpret_cast<const __half2*>(&r1);
    const float2 s0a = __half22float2(h0[0]);  // t:   b0,b1
    const float2 s0b = __half22float2(h0[1]);  // t:   b2,b3
    const float2 s1a = __half22float2(h1[0]);  // t+1: b0,b1
    const float2 s1b = __half22float2(h1[1]);  // t+1: b2,b3

    a0 += w * (s0a.x + al * (s1a.x - s0a.x));
    a1 += w * (s0a.y + al * (s1a.y - s0a.y));
    a2 += w * (s0b.x + al * (s1b.x - s0b.x));
    a3 += w * (s0b.y + al * (s1b.y - s0b.y));

    // Commit staged registers to the other buffer; one barrier per iter.
    if (more) {
      float4* dst = reinterpret_cast<float4*>(&sbuf[(g + 1) & 1][0]);
#pragma unroll
      for (int i = 0; i < 4; ++i) dst[tid + i * TPB] = st[i];
      lcur = lnext;
    }
    __syncthreads();
  }

  // Reduce the 4 det-slots of each pixel (consecutive lanes) via quad shuffles.
  a0 += __shfl_xor(a0, 1);  a0 += __shfl_xor(a0, 2);
  a1 += __shfl_xor(a1, 1);  a1 += __shfl_xor(a1, 2);
  a2 += __shfl_xor(a2, 1);  a2 += __shfl_xor(a2, 2);
  a3 += __shfl_xor(a3, 1);  a3 += __shfl_xor(a3, 2);

  if (slot == 0) {  // lanes 0,4,..,60 -> 16 consecutive pixels = 64 B/batch
    const float nrm = 1.0f / 63.5f;  // sum(apod) == 63.5 analytically
    __builtin_nontemporal_store(a0 * nrm, out + 0 * NPIX + p);
    __builtin_nontemporal_store(a1 * nrm, out + 1 * NPIX + p);
    __builtin_nontemporal_store(a2 * nrm, out + 2 * NPIX + p);
    __builtin_nontemporal_store(a3 * nrm, out + 3 * NPIX + p);
  }
}

// Fallback (no workspace): direct fp32 gather from original layout.
__global__ __launch_bounds__(256) void das_fallback_kernel(
    const float* __restrict__ lut, const float* __restrict__ S,
    float* __restrict__ out) {
  const int lane = threadIdx.x & 63;
  const int p = blockIdx.x * 4 + (threadIdx.x >> 6);

  const float4 lv =
      reinterpret_cast<const float4*>(lut + (size_t)p * 2 * N_DET)[lane];

  float acc0 = 0.f, acc1 = 0.f, acc2 = 0.f, acc3 = 0.f;
  float wsum = 0.f;

#pragma unroll
  for (int j = 0; j < 2; ++j) {
    const int d = 2 * lane + j;
    const float tof = j ? lv.z : lv.x;
    const float a   = j ? lv.w : lv.y;
    const float kf = floorf(tof);
    const bool valid = (kf >= 0.0f) && (kf < (float)(N_T - 1));
    const float kcl = fminf(fmaxf(kf, 0.0f), (float)(N_T - 2));
    const int k0 = (int)kcl;
    const float apd =
        0.5f - 0.5f * cosf(6.28318530717958647692f *
                           (1.0f / (float)(N_DET - 1)) * (float)d);
    wsum += apd;
    const float w = valid ? apd : 0.0f;
    const float om = 1.0f - a;
    const float* row = S + (size_t)d * N_T + k0;
    acc0 += w * (om * row[0 * N_DET * N_T] + a * row[0 * N_DET * N_T + 1]);
    acc1 += w * (om * row[1 * N_DET * N_T] + a * row[1 * N_DET * N_T + 1]);
    acc2 += w * (om * row[2 * N_DET * N_T] + a * row[2 * N_DET * N_T + 1]);
    acc3 += w * (om * row[3 * N_DET * N_T] + a * row[3 * N_DET * N_T + 1]);
  }

#pragma unroll
  for (int off = 32; off > 0; off >>= 1) {
    acc0 += __shfl_xor(acc0, off);
    acc1 += __shfl_xor(acc1, off);
    acc2 += __shfl_xor(acc2, off);
    acc3 += __shfl_xor(acc3, off);
    wsum += __shfl_xor(wsum, off);
  }

  if (lane == 0) {
    const float inv = 1.0f / fmaxf(wsum, 1.17549435e-38f);
    out[0 * NPIX + p] = acc0 * inv;
    out[1 * NPIX + p] = acc1 * inv;
    out[2 * NPIX + p] = acc2 * inv;
    out[3 * NPIX + p] = acc3 * inv;
  }
}

extern "C" void kernel_launch(void* const* d_in, const int* in_sizes, int n_in,
                              void* d_out, int out_size, void* d_ws, size_t ws_size,
                              hipStream_t stream) {
  const float* sino = (const float*)d_in[0];  // (B,1,N_DET,N_T) fp32
  const float* lut  = (const float*)d_in[1];  // (NY,NX,N_DET,2) fp32
  float* out = (float*)d_out;                 // (B,1,NY,NX) fp32

  const size_t need = (size_t)N_DET * N_T * 8;  // 2 MB packed ws
  if (ws_size >= need) {
    float2* ws = (float2*)d_ws;
    sino_pack_kernel<<<(N_DET * N_T) / 256, 256, 0, stream>>>(sino, ws);
    das_kloop_kernel<<<NPIX / PT, TPB, 0, stream>>>(lut, ws, out);
  } else {
    das_fallback_kernel<<<NPIX / 4, 256, 0, stream>>>(lut, sino, out);
  }
}